// Round 1
// baseline (1330.275 us; speedup 1.0000x reference)
//
#include <hip/hip_runtime.h>
#include <hip/hip_bf16.h>

typedef __attribute__((ext_vector_type(8))) short short8;
typedef __attribute__((ext_vector_type(4))) short short4v;
typedef __attribute__((ext_vector_type(4))) float floatx4;

#define B_DIM 64
#define L_SEQ 2048
#define D_H   64
#define BQ    32              // q-rows per block
#define SSTR  2056            // scores LDS row stride in bf16 elems (2048 + 8 pad)
#define VSTR  136             // V-transpose LDS row stride in bf16 elems (128 + 8 pad)

#define LDS_SCORES_BYTES (BQ * SSTR * 2)      // 131584
#define LDS_VT_BYTES     (64 * VSTR * 2)      // 17408
#define LDS_PMAX_OFF     (LDS_SCORES_BYTES + LDS_VT_BYTES)          // 148992
#define LDS_MROW_OFF     (LDS_PMAX_OFF + 4 * 32 * 4)                // +512
#define LDS_RINV_OFF     (LDS_MROW_OFF + 32 * 4)                    // +128
#define LDS_TOTAL        (LDS_RINV_OFF + 32 * 4)                    // 149760

__device__ __forceinline__ short f2bf(float f) {
    unsigned u = __builtin_bit_cast(unsigned, f);
    u += 0x7FFFu + ((u >> 16) & 1u);
    return (short)(u >> 16);
}
__device__ __forceinline__ float bf2f(short h) {
    unsigned u = ((unsigned)(unsigned short)h) << 16;
    return __builtin_bit_cast(float, u);
}

__global__ __launch_bounds__(512, 2)
void sdpa_kernel(const float* __restrict__ q, const float* __restrict__ k,
                 const float* __restrict__ v, const void* __restrict__ mask,
                 float* __restrict__ out, float* __restrict__ attn)
{
    extern __shared__ char lds_raw[];
    short* s_scores = (short*)lds_raw;
    short* s_vt     = (short*)(lds_raw + LDS_SCORES_BYTES);
    float* s_pmax   = (float*)(lds_raw + LDS_PMAX_OFF);   // [4 ksec][32 rows]
    float* s_mrow   = (float*)(lds_raw + LDS_MROW_OFF);   // [32]
    float* s_rinv   = (float*)(lds_raw + LDS_RINV_OFF);   // [32]

    const int tid  = threadIdx.x;
    const int wave = tid >> 6;
    const int lane = tid & 63;
    const int l16  = lane & 15;
    const int l4   = lane >> 4;          // 0..3
    const int b     = blockIdx.y;
    const int qbase = blockIdx.x * BQ;

    // ---------- mask element-size detection (uniform, deterministic) ----------
    // word mode (4B elems, int32 0/1 or f32 0/1.0) iff first 64 words all in
    // {0,1,0x3F800000}; a raw-bool(uint8) mask fails this with prob ~1-1e-30.
    const unsigned* mwords = (const unsigned*)mask;
    bool wordMode = true;
    #pragma unroll 8
    for (int i = 0; i < 64; ++i) {
        unsigned w = mwords[i];
        if (!(w == 0u || w == 1u || w == 0x3F800000u)) wordMode = false;
    }

    // ---------- Phase 1: S = QK^T / 8 -> LDS (bf16), track row max ----------
    const int qsub = wave >> 2;          // 0..1 : which 16-row half of the q tile
    const int ksec = wave & 3;           // 0..3 : which 512-col section of k

    short8 aq[2];
    {
        const float* qrow = q + ((size_t)b * L_SEQ + qbase + qsub * 16 + l16) * D_H + l4 * 8;
        #pragma unroll
        for (int h = 0; h < 2; ++h) {
            float4 f0 = *(const float4*)(qrow + h * 32);
            float4 f1 = *(const float4*)(qrow + h * 32 + 4);
            short8 a;
            a[0] = f2bf(f0.x); a[1] = f2bf(f0.y); a[2] = f2bf(f0.z); a[3] = f2bf(f0.w);
            a[4] = f2bf(f1.x); a[5] = f2bf(f1.y); a[6] = f2bf(f1.z); a[7] = f2bf(f1.w);
            aq[h] = a;
        }
    }

    float pm[4] = {-3e38f, -3e38f, -3e38f, -3e38f};
    for (int t = 0; t < 32; ++t) {
        const int kt = ksec * 32 + t;    // global 16-wide k tile
        const float* krow = k + ((size_t)b * L_SEQ + kt * 16 + l16) * D_H + l4 * 8;
        floatx4 c = {0.f, 0.f, 0.f, 0.f};
        #pragma unroll
        for (int h = 0; h < 2; ++h) {
            float4 f0 = *(const float4*)(krow + h * 32);
            float4 f1 = *(const float4*)(krow + h * 32 + 4);
            short8 bk;
            bk[0] = f2bf(f0.x); bk[1] = f2bf(f0.y); bk[2] = f2bf(f0.z); bk[3] = f2bf(f0.w);
            bk[4] = f2bf(f1.x); bk[5] = f2bf(f1.y); bk[6] = f2bf(f1.z); bk[7] = f2bf(f1.w);
            c = __builtin_amdgcn_mfma_f32_16x16x32_bf16(aq[h], bk, c, 0, 0, 0);
        }
        // c[r] = S[q = qsub*16 + l4*4 + r][col = kt*16 + l16]
        #pragma unroll
        for (int r = 0; r < 4; ++r) {
            float s = c[r] * 0.125f;
            pm[r] = fmaxf(pm[r], s);
            s_scores[(qsub * 16 + l4 * 4 + r) * SSTR + kt * 16 + l16] = f2bf(s);
        }
    }
    // reduce partial max across the 16 column-lanes of each quarter-wave
    #pragma unroll
    for (int r = 0; r < 4; ++r) {
        float m = pm[r];
        #pragma unroll
        for (int off = 1; off < 16; off <<= 1) m = fmaxf(m, __shfl_xor(m, off, 64));
        pm[r] = m;
    }
    if (l16 == 0) {
        #pragma unroll
        for (int r = 0; r < 4; ++r)
            s_pmax[ksec * 32 + qsub * 16 + l4 * 4 + r] = pm[r];
    }
    __syncthreads();

    if (tid < 32) {
        float m = s_pmax[tid];
        m = fmaxf(m, s_pmax[32 + tid]);
        m = fmaxf(m, s_pmax[64 + tid]);
        m = fmaxf(m, s_pmax[96 + tid]);
        s_mrow[tid] = m;
    }
    __syncthreads();

    // ---------- Phase 2a: e = exp(s-m) (masked), row sums, write attn ----------
    const int qa = tid >> 4;             // 0..31 row
    const int ca = tid & 15;             // 16 threads per row
    const float mrow = s_mrow[qa];
    const size_t rowbase = ((size_t)b * L_SEQ + qbase + qa) * (size_t)L_SEQ;

    float psum = 0.f;
    for (int j = 0; j < 16; ++j) {
        const int c0 = ca * 8 + j * 128;
        short* sp = s_scores + qa * SSTR + c0;
        short8 sv = *(short8*)sp;
        unsigned mbits = 0;
        if (wordMode) {
            const unsigned* mp = mwords + rowbase + c0;
            uint4 a = *(const uint4*)mp;
            uint4 bb = *(const uint4*)(mp + 4);
            mbits = (a.x ? 1u : 0u) | (a.y ? 2u : 0u) | (a.z ? 4u : 0u) | (a.w ? 8u : 0u) |
                    (bb.x ? 16u : 0u) | (bb.y ? 32u : 0u) | (bb.z ? 64u : 0u) | (bb.w ? 128u : 0u);
        } else {
            const unsigned char* mp = (const unsigned char*)mask + rowbase + c0;
            uint2 mm = *(const uint2*)mp;
            #pragma unroll
            for (int i = 0; i < 4; ++i) {
                if ((mm.x >> (8 * i)) & 0xFFu) mbits |= (1u << i);
                if ((mm.y >> (8 * i)) & 0xFFu) mbits |= (1u << (i + 4));
            }
        }
        short8 ev;
        float lsum = 0.f;
        #pragma unroll
        for (int i = 0; i < 8; ++i) {
            float s = bf2f(sv[i]);
            float e = ((mbits >> i) & 1u) ? 0.f : exp2f((s - mrow) * 1.44269504f);
            short eb = f2bf(e);
            ev[i] = eb;
            lsum += bf2f(eb);            // sum the rounded values for consistency
        }
        *(short8*)sp = ev;
        psum += lsum;
    }
    #pragma unroll
    for (int off = 1; off < 16; off <<= 1) psum += __shfl_xor(psum, off, 64);
    if (ca == 0) s_rinv[qa] = psum;
    __syncthreads();
    if (tid < 32) s_rinv[tid] = 1.0f / s_rinv[tid];
    __syncthreads();

    {
        const float ri = s_rinv[qa];
        float* arow = attn + rowbase;
        for (int j = 0; j < 16; ++j) {
            const int c0 = ca * 8 + j * 128;
            short8 sv = *(short8*)(s_scores + qa * SSTR + c0);
            float4 o0, o1;
            o0.x = bf2f(sv[0]) * ri; o0.y = bf2f(sv[1]) * ri;
            o0.z = bf2f(sv[2]) * ri; o0.w = bf2f(sv[3]) * ri;
            o1.x = bf2f(sv[4]) * ri; o1.y = bf2f(sv[5]) * ri;
            o1.z = bf2f(sv[6]) * ri; o1.w = bf2f(sv[7]) * ri;
            *(float4*)(arow + c0)     = o0;
            *(float4*)(arow + c0 + 4) = o1;
        }
    }

    // ---------- Phase 2b: O = (P/l) V via MFMA with LDS-transposed V ----------
    const int dg = wave & 3;             // 16-wide d group
    const int td = tid & 63;             // d index for staging
    const int tk = tid >> 6;             // 16-row k group for staging (== wave)
    floatx4 oacc = {0.f, 0.f, 0.f, 0.f};

    for (int ch = 0; ch < 16; ++ch) {
        __syncthreads();                 // protect previous chunk's reads
        {
            const float* vp = v + ((size_t)b * L_SEQ + ch * 128 + tk * 16) * D_H + td;
            #pragma unroll
            for (int i = 0; i < 16; i += 4) {
                float f0 = vp[(i + 0) * D_H];
                float f1 = vp[(i + 1) * D_H];
                float f2 = vp[(i + 2) * D_H];
                float f3 = vp[(i + 3) * D_H];
                short4v pk = { f2bf(f0), f2bf(f1), f2bf(f2), f2bf(f3) };
                *(short4v*)(s_vt + td * VSTR + tk * 16 + i) = pk;
            }
        }
        __syncthreads();
        #pragma unroll
        for (int s = 0; s < 4; ++s) {
            const int koff = ch * 128 + s * 32;
            short8 pf = *(short8*)(s_scores + (qsub * 16 + l16) * SSTR + koff + l4 * 8);
            short8 vf = *(short8*)(s_vt + (dg * 16 + l16) * VSTR + s * 32 + l4 * 8);
            oacc = __builtin_amdgcn_mfma_f32_16x16x32_bf16(pf, vf, oacc, 0, 0, 0);
        }
    }

    #pragma unroll
    for (int r = 0; r < 4; ++r) {
        const int qrow_l = qsub * 16 + l4 * 4 + r;
        float val = oacc[r] * s_rinv[qrow_l];
        out[((size_t)b * L_SEQ + qbase + qrow_l) * D_H + dg * 16 + l16] = val;
    }
}

extern "C" void kernel_launch(void* const* d_in, const int* in_sizes, int n_in,
                              void* d_out, int out_size, void* d_ws, size_t ws_size,
                              hipStream_t stream) {
    const float* q = (const float*)d_in[0];
    const float* k = (const float*)d_in[1];
    const float* v = (const float*)d_in[2];
    const void* mask = d_in[3];
    float* out  = (float*)d_out;
    float* attn = out + (size_t)B_DIM * L_SEQ * D_H;

    dim3 grid(L_SEQ / BQ, B_DIM, 1);
    dim3 block(512, 1, 1);
    hipLaunchKernelGGL(sdpa_kernel, grid, block, LDS_TOTAL, stream,
                       q, k, v, mask, out, attn);
}

// Round 2
// 1098.520 us; speedup vs baseline: 1.2110x; 1.2110x over previous
//
#include <hip/hip_runtime.h>

typedef __attribute__((ext_vector_type(8))) short short8;
typedef __attribute__((ext_vector_type(4))) float floatx4;

#define B_DIM 64
#define L_SEQ 2048
#define D_H   64
#define BQ    16

// ---- LDS layout (bytes) ----
#define SC_BYTES  (BQ * L_SEQ * 2)          // 65536: scores/e, [16][2048] bf16, swizzled
#define VT_OFF    SC_BYTES                  // 8192: V tile [64 d][64 k] bf16 (reused as [2][16][64] f32)
#define VT_BYTES  8192
#define RS_OFF    (VT_OFF + VT_BYTES)       // 64: row sums [16] f32
#define RI_OFF    (RS_OFF + 64)             // 64: row inv  [16] f32
#define LDS_TOTAL (RI_OFF + 64)             // 73856 -> 2 blocks/CU

__device__ __forceinline__ short f2bf(float f) {
    unsigned u = __builtin_bit_cast(unsigned, f);
    u += 0x7FFFu + ((u >> 16) & 1u);
    return (short)(u >> 16);
}
__device__ __forceinline__ float bf2f(short h) {
    unsigned u = ((unsigned)(unsigned short)h) << 16;
    return __builtin_bit_cast(float, u);
}
// 16B-slot XOR swizzle: even bank spread for b128 on rows (stride 4096 == 0 mod 128B)
__device__ __forceinline__ int sidx(int row, int colbyte) {
    return row * 4096 + (colbyte ^ ((row & 7) << 4));
}
__device__ __forceinline__ int vidx(int d, int kbyte) {
    return d * 128 + (kbyte ^ ((d & 7) << 4));
}

__global__ __launch_bounds__(512, 4)
void sdpa_kernel(const float* __restrict__ q, const float* __restrict__ k,
                 const float* __restrict__ v, const void* __restrict__ mask,
                 float* __restrict__ out, float* __restrict__ attn)
{
    extern __shared__ char lds[];
    float* s_rsum = (float*)(lds + RS_OFF);
    float* s_rinv = (float*)(lds + RI_OFF);

    const int tid  = threadIdx.x;
    const int wave = tid >> 6;
    const int lane = tid & 63;
    const int l16  = lane & 15;
    const int l4   = lane >> 4;

    // bijective XCD swizzle: whole batches pinned to one XCD's L2
    const int bid  = blockIdx.x;                 // 8192 blocks, 8192%8==0
    const int sbid = (bid & 7) * 1024 + (bid >> 3);
    const int b     = sbid >> 7;                 // 128 blocks per batch
    const int qbase = (sbid & 127) * BQ;

    // ---------- mask element-size detection (uniform) ----------
    const unsigned* mwords = (const unsigned*)mask;
    bool wordMode = true;
    #pragma unroll 8
    for (int i = 0; i < 64; ++i) {
        unsigned w = mwords[i];
        if (!(w == 0u || w == 1u || w == 0x3F800000u)) wordMode = false;
    }

    // ---------- Phase 1: S = QK^T / 8 -> swizzled LDS (bf16). No max pass. ----------
    short8 aq[2];
    {
        const float* qrow = q + ((size_t)b * L_SEQ + qbase + l16) * D_H + l4 * 8;
        #pragma unroll
        for (int h = 0; h < 2; ++h) {
            float4 f0 = *(const float4*)(qrow + h * 32);
            float4 f1 = *(const float4*)(qrow + h * 32 + 4);
            short8 a;
            a[0] = f2bf(f0.x); a[1] = f2bf(f0.y); a[2] = f2bf(f0.z); a[3] = f2bf(f0.w);
            a[4] = f2bf(f1.x); a[5] = f2bf(f1.y); a[6] = f2bf(f1.z); a[7] = f2bf(f1.w);
            aq[h] = a;
        }
    }
    for (int t = 0; t < 16; ++t) {
        const int kt = wave * 16 + t;            // this wave's 256-col section
        const float* krow = k + ((size_t)b * L_SEQ + kt * 16 + l16) * D_H + l4 * 8;
        floatx4 c = {0.f, 0.f, 0.f, 0.f};
        #pragma unroll
        for (int h = 0; h < 2; ++h) {
            float4 f0 = *(const float4*)(krow + h * 32);
            float4 f1 = *(const float4*)(krow + h * 32 + 4);
            short8 bk;
            bk[0] = f2bf(f0.x); bk[1] = f2bf(f0.y); bk[2] = f2bf(f0.z); bk[3] = f2bf(f0.w);
            bk[4] = f2bf(f1.x); bk[5] = f2bf(f1.y); bk[6] = f2bf(f1.z); bk[7] = f2bf(f1.w);
            c = __builtin_amdgcn_mfma_f32_16x16x32_bf16(aq[h], bk, c, 0, 0, 0);
        }
        #pragma unroll
        for (int r = 0; r < 4; ++r)
            *(short*)(lds + sidx(l4 * 4 + r, (kt * 16 + l16) * 2)) = f2bf(c[r] * 0.125f);
    }
    __syncthreads();

    // ---------- Phase 2a: e = mask ? 0 : exp(s); row sums; write attn ----------
    const int qa = tid >> 5;                     // 0..15
    const int ca = tid & 31;                     // 32 threads/row
    const size_t rowbase = ((size_t)b * L_SEQ + qbase + qa) * (size_t)L_SEQ;

    float psum = 0.f;
    for (int j = 0; j < 8; ++j) {
        const int col = ca * 8 + j * 256;
        short8 sv = *(short8*)(lds + sidx(qa, col * 2));
        unsigned mbits = 0;
        if (wordMode) {
            const unsigned* mp = mwords + rowbase + col;
            uint4 a = *(const uint4*)mp;
            uint4 bb = *(const uint4*)(mp + 4);
            mbits = (a.x ? 1u : 0u) | (a.y ? 2u : 0u) | (a.z ? 4u : 0u) | (a.w ? 8u : 0u) |
                    (bb.x ? 16u : 0u) | (bb.y ? 32u : 0u) | (bb.z ? 64u : 0u) | (bb.w ? 128u : 0u);
        } else {
            const unsigned char* mp = (const unsigned char*)mask + rowbase + col;
            uint2 mm = *(const uint2*)mp;
            #pragma unroll
            for (int i = 0; i < 4; ++i) {
                if ((mm.x >> (8 * i)) & 0xFFu) mbits |= (1u << i);
                if ((mm.y >> (8 * i)) & 0xFFu) mbits |= (1u << (i + 4));
            }
        }
        short8 ev;
        float lsum = 0.f;
        #pragma unroll
        for (int i = 0; i < 8; ++i) {
            float s = bf2f(sv[i]);
            float e = ((mbits >> i) & 1u) ? 0.f : exp2f(s * 1.44269504f);
            short eb = f2bf(e);
            ev[i] = eb;
            lsum += bf2f(eb);
        }
        *(short8*)(lds + sidx(qa, col * 2)) = ev;
        psum += lsum;
    }
    #pragma unroll
    for (int off = 1; off < 32; off <<= 1) psum += __shfl_xor(psum, off, 64);
    if (ca == 0) s_rsum[qa] = psum;
    __syncthreads();
    if (tid < 16) s_rinv[tid] = 1.0f / s_rsum[tid];
    __syncthreads();

    {
        const float ri = s_rinv[qa];
        float* arow = attn + rowbase;
        for (int j = 0; j < 8; ++j) {
            const int col = ca * 8 + j * 256;
            short8 sv = *(short8*)(lds + sidx(qa, col * 2));
            float4 o0, o1;
            o0.x = bf2f(sv[0]) * ri; o0.y = bf2f(sv[1]) * ri;
            o0.z = bf2f(sv[2]) * ri; o0.w = bf2f(sv[3]) * ri;
            o1.x = bf2f(sv[4]) * ri; o1.y = bf2f(sv[5]) * ri;
            o1.z = bf2f(sv[6]) * ri; o1.w = bf2f(sv[7]) * ri;
            *(float4*)(arow + col)     = o0;
            *(float4*)(arow + col + 4) = o1;
        }
    }

    // ---------- Phase 2b: O = e·V (64-k chunks, k-split over 8 waves) ----------
    const int dg = wave & 3;                     // d-group (16 cols)
    const int kh = wave >> 2;                    // k-half within chunk
    const int td = tid & 63;                     // d for staging
    const int tk = tid >> 6;                     // 8-row k group for staging
    floatx4 oacc = {0.f, 0.f, 0.f, 0.f};

    for (int ch = 0; ch < 32; ++ch) {
        __syncthreads();
        {
            const float* vp = v + ((size_t)b * L_SEQ + ch * 64 + tk * 8) * D_H + td;
            short8 pk;
            #pragma unroll
            for (int i = 0; i < 8; ++i) pk[i] = f2bf(vp[i * D_H]);
            *(short8*)(lds + VT_OFF + vidx(td, tk * 16)) = pk;
        }
        __syncthreads();
        short8 pf = *(short8*)(lds + sidx(l16, ch * 128 + kh * 64 + l4 * 16));
        short8 vf = *(short8*)(lds + VT_OFF + vidx(dg * 16 + l16, kh * 64 + l4 * 16));
        oacc = __builtin_amdgcn_mfma_f32_16x16x32_bf16(pf, vf, oacc, 0, 0, 0);
    }

    // combine the two k-halves via LDS (reuse V-tile region as [2][16][64] f32)
    __syncthreads();
    float* s_ored = (float*)(lds + VT_OFF);
    #pragma unroll
    for (int r = 0; r < 4; ++r)
        s_ored[kh * 1024 + (l4 * 4 + r) * 64 + dg * 16 + l16] = oacc[r];
    __syncthreads();
    if (tid < 256) {
        const int qo = tid >> 4, dc = tid & 15;
        float4 a = *(float4*)(s_ored + qo * 64 + dc * 4);
        float4 c = *(float4*)(s_ored + 1024 + qo * 64 + dc * 4);
        const float ri = s_rinv[qo];
        float4 o;
        o.x = (a.x + c.x) * ri; o.y = (a.y + c.y) * ri;
        o.z = (a.z + c.z) * ri; o.w = (a.w + c.w) * ri;
        *(float4*)(out + ((size_t)b * L_SEQ + qbase + qo) * D_H + dc * 4) = o;
    }
}

extern "C" void kernel_launch(void* const* d_in, const int* in_sizes, int n_in,
                              void* d_out, int out_size, void* d_ws, size_t ws_size,
                              hipStream_t stream) {
    const float* q = (const float*)d_in[0];
    const float* k = (const float*)d_in[1];
    const float* v = (const float*)d_in[2];
    const void* mask = d_in[3];
    float* out  = (float*)d_out;
    float* attn = out + (size_t)B_DIM * L_SEQ * D_H;

    dim3 grid(B_DIM * (L_SEQ / BQ), 1, 1);       // 8192 blocks
    dim3 block(512, 1, 1);
    hipLaunchKernelGGL(sdpa_kernel, grid, block, LDS_TOTAL, stream,
                       q, k, v, mask, out, attn);
}